// Round 2
// baseline (4384.174 us; speedup 1.0000x reference)
//
#include <hip/hip_runtime.h>
#include <stdint.h>

typedef uint16_t u16;
typedef uint32_t u32;

#define DEVI __device__ __forceinline__

DEVI float b2f(u16 u) { return __uint_as_float(((u32)u) << 16); }
DEVI float blo(u32 u) { return __uint_as_float(u << 16); }
DEVI float bhi(u32 u) { return __uint_as_float(u & 0xffff0000u); }
DEVI u16 f2b(float f) {
  u32 x = __float_as_uint(f);
  return (u16)((x + 0x7fffu + ((x >> 16) & 1u)) >> 16);
}
DEVI u32 pack2(float a, float b) { return (u32)f2b(a) | ((u32)f2b(b) << 16); }
DEVI float sigm(float x) { return 1.f / (1.f + __expf(-x)); }

typedef __bf16 bf16x8 __attribute__((ext_vector_type(8)));
typedef float f32x4 __attribute__((ext_vector_type(4)));

// ---------------- input dtype detect: 0 = bf16, 1 = fp32 ----------------
// bf16 randn values have exponent field <= ~129; fp32 low-half u16s are ~uniform bits.
__global__ void detect_kernel(const u16* __restrict__ x, int* __restrict__ flag) {
  if (threadIdx.x == 0 && blockIdx.x == 0) {
    int f = 0;
    for (int i = 0; i < 64; ++i) {
      u16 u = x[2 * i];  // low half if fp32
      int e = (u >> 7) & 0xFF;
      if (e > 131) f = 1;  // |val| >= 32 impossible for randn bf16
    }
    *flag = f;
  }
}

__global__ void convert_kernel(const void* __restrict__ src, u16* __restrict__ dst, int n,
                               const int* __restrict__ flag) {
  int i = blockIdx.x * 256 + threadIdx.x;
  if (i >= n) return;
  if (*flag)
    dst[i] = f2b(((const float*)src)[i]);
  else
    dst[i] = ((const u16*)src)[i];
}

// ---------------- GEMM: C[m,n] = act(A[m,:] . Bt[n,:] + bias[n]) -> bf16 ----------------
// A [Mtot,512] bf16, Bt [Ntot,512] bf16 (pre-transposed weights). 128x128 tile, BK=64,
// 256 threads. Register staging (m92 pattern) + XOR-swizzled LDS (slot = kchunk ^ (row&7)).
template <int ACT>
__global__ __launch_bounds__(256, 2) void gemm_bt(
    const u16* __restrict__ A, const u16* __restrict__ Bt,
    const u16* __restrict__ bias, u16* __restrict__ Co, int Mtot, int Ntot) {
  __shared__ __align__(16) u16 aT[128 * 64];
  __shared__ __align__(16) u16 bT[128 * 64];
  const int tid = threadIdx.x;
  const int lane = tid & 63;
  const int w = tid >> 6;
  const int m0 = blockIdx.x * 128;
  const int n0 = blockIdx.y * 128;
  const int wm = (w & 1) << 6;
  const int wn = (w >> 1) << 6;

  f32x4 acc[4][4] = {};

  const u16* ga[4];
  const u16* gb[4];
#pragma unroll
  for (int q = 0; q < 4; ++q) {
    int j = q * 256 + tid;
    int r = j >> 3, s = j & 7;
    int c = (s ^ (r & 7)) * 8;  // swizzle folded into global column
    int ra = m0 + r;
    if (ra >= Mtot) ra = Mtot - 1;
    ga[q] = A + (size_t)ra * 512 + c;
    gb[q] = Bt + (size_t)(n0 + r) * 512 + c;
  }

  for (int ko = 0; ko < 8; ++ko) {
    const int k0 = ko * 64;
    uint4 av[4], bv4[4];
#pragma unroll
    for (int q = 0; q < 4; ++q) {
      av[q] = *(const uint4*)(ga[q] + k0);
      bv4[q] = *(const uint4*)(gb[q] + k0);
    }
    __syncthreads();  // prior iter's LDS reads complete
#pragma unroll
    for (int q = 0; q < 4; ++q) {
      int j = q * 256 + tid;
      *(uint4*)(aT + j * 8) = av[q];
      *(uint4*)(bT + j * 8) = bv4[q];
    }
    __syncthreads();
#pragma unroll
    for (int ks = 0; ks < 2; ++ks) {
      bf16x8 af[4], bfr[4];
#pragma unroll
      for (int i = 0; i < 4; ++i) {
        int cch = ks * 4 + (lane >> 4);
        int r = wm + i * 16 + (lane & 15);
        af[i] = *(const bf16x8*)(aT + (r * 8 + (cch ^ (r & 7))) * 8);
        int rn = wn + i * 16 + (lane & 15);
        bfr[i] = *(const bf16x8*)(bT + (rn * 8 + (cch ^ (rn & 7))) * 8);
      }
#pragma unroll
      for (int i = 0; i < 4; ++i)
#pragma unroll
        for (int jn = 0; jn < 4; ++jn)
          acc[i][jn] = __builtin_amdgcn_mfma_f32_16x16x32_bf16(af[i], bfr[jn], acc[i][jn], 0, 0, 0);
    }
  }

  const int cl = lane & 15;
  const int rg = lane >> 4;
#pragma unroll
  for (int jn = 0; jn < 4; ++jn) {
    int col = n0 + wn + jn * 16 + cl;
    float bv = b2f(bias[col]);
#pragma unroll
    for (int i = 0; i < 4; ++i) {
      int rowb = m0 + wm + i * 16 + rg * 4;
#pragma unroll
      for (int rr = 0; rr < 4; ++rr) {
        int row = rowb + rr;
        if (row < Mtot) {
          float vv = acc[i][jn][rr] + bv;
          if (ACT) vv = fmaxf(vv, 0.f);
          Co[(size_t)row * Ntot + col] = f2b(vv);
        }
      }
    }
  }
}

// ---------------- weight transpose [K,N] bf16 -> [N,K] bf16 ----------------
__global__ __launch_bounds__(256) void transpose_kernel(const u16* __restrict__ in,
                                                        u16* __restrict__ outb, int K, int N) {
  __shared__ u16 tile[32][33];
  const int tx = threadIdx.x & 31, ty = threadIdx.x >> 5;
  const int bx = blockIdx.x * 32;  // N dim
  const int by = blockIdx.y * 32;  // K dim
#pragma unroll
  for (int i = 0; i < 32; i += 8) tile[ty + i][tx] = in[(size_t)(by + ty + i) * N + bx + tx];
  __syncthreads();
#pragma unroll
  for (int i = 0; i < 32; i += 8) outb[(size_t)(bx + ty + i) * K + by + tx] = tile[tx][ty + i];
}

// ---------------- tanh(memory) -> bf16 ----------------
__global__ void tanhmem_kernel(const u16* __restrict__ mi, u16* __restrict__ th, int n8) {
  int i = blockIdx.x * 256 + threadIdx.x;
  if (i >= n8) return;
  uint4 u = ((const uint4*)mi)[i];
  uint4 t;
  t.x = pack2(tanhf(blo(u.x)), tanhf(bhi(u.x)));
  t.y = pack2(tanhf(blo(u.y)), tanhf(bhi(u.y)));
  t.z = pack2(tanhf(blo(u.z)), tanhf(bhi(u.z)));
  t.w = pack2(tanhf(blo(u.w)), tanhf(bhi(u.w)));
  ((uint4*)th)[i] = t;
}

// ---------------- rmean[b,c] = mean_t relu(rep_w[c] * inp[b,t,c]) ----------------
__global__ void redmean_kernel(const u16* __restrict__ inp, const u16* __restrict__ repw,
                               u16* __restrict__ outb) {
  const int b = blockIdx.x;
  const int c = blockIdx.y * 256 + threadIdx.x;
  const float rw = b2f(repw[c]);
  float s = 0.f;
  for (int t = 0; t < 128; ++t)
    s += fmaxf(rw * b2f(inp[(size_t)(b * 128 + t) * 512 + c]), 0.f);
  outb[b * 512 + c] = f2b(s * (1.f / 128.f));
}

// ---------------- LayerNorm(src + add) -> dst ----------------
__global__ __launch_bounds__(64) void ln_kernel(const u16* __restrict__ src,
                                                const u16* __restrict__ addb,
                                                u16* __restrict__ dst,
                                                const u16* __restrict__ g,
                                                const u16* __restrict__ bb) {
  const int row = blockIdx.x;
  const int lane = threadIdx.x;
  const u16* srow = src + (size_t)row * 512;
  const u16* arow = addb + (size_t)row * 512;
  float x[8];
  float s = 0.f;
#pragma unroll
  for (int i = 0; i < 8; ++i) {
    int c = lane + i * 64;
    x[i] = b2f(srow[c]) + b2f(arow[c]);
    s += x[i];
  }
#pragma unroll
  for (int off = 32; off > 0; off >>= 1) s += __shfl_xor(s, off, 64);
  const float mu = s * (1.f / 512.f);
  float v = 0.f;
#pragma unroll
  for (int i = 0; i < 8; ++i) {
    float d = x[i] - mu;
    v = fmaf(d, d, v);
  }
#pragma unroll
  for (int off = 32; off > 0; off >>= 1) v += __shfl_xor(v, off, 64);
  const float rstd = rsqrtf(v * (1.f / 512.f) + 1e-5f);
  u16* orow = dst + (size_t)row * 512;
#pragma unroll
  for (int i = 0; i < 8; ++i) {
    int c = lane + i * 64;
    orow[c] = f2b(fmaf((x[i] - mu) * rstd, b2f(g[c]), b2f(bb[c])));
  }
}

// ---------------- attention 1: 1290 queries (mem), 128 keys (inp), top-8 mask ----------------
__global__ __launch_bounds__(256, 2) void attn1_kernel(const u16* __restrict__ q,
                                                       const u16* __restrict__ kb,
                                                       const u16* __restrict__ vb,
                                                       u16* __restrict__ o) {
  __shared__ __align__(16) float ks_[128][64];
  __shared__ __align__(16) u16 vs[128][72];
  const int tid = threadIdx.x;
  const int bh = blockIdx.y;
  const int b = bh >> 3, h = bh & 7;

  for (int i = tid; i < 128 * 64; i += 256) {
    int t = i >> 6, d = i & 63;
    size_t gidx = (size_t)(b * 128 + t) * 512 + h * 64 + d;
    ks_[t][d] = b2f(kb[gidx]);
    vs[t][d] = vb[gidx];
  }
  __syncthreads();

  const int m = blockIdx.x * 256 + tid;
  const bool active = (m < 1290);
  const int mm = active ? m : 0;

  float qr[64];
  {
    const u16* qrow = q + (size_t)(b * 1290 + mm) * 512 + h * 64;
#pragma unroll
    for (int d8 = 0; d8 < 8; ++d8) {
      uint4 u = *(const uint4*)(qrow + d8 * 8);
      qr[d8 * 8 + 0] = blo(u.x); qr[d8 * 8 + 1] = bhi(u.x);
      qr[d8 * 8 + 2] = blo(u.y); qr[d8 * 8 + 3] = bhi(u.y);
      qr[d8 * 8 + 4] = blo(u.z); qr[d8 * 8 + 5] = bhi(u.z);
      qr[d8 * 8 + 6] = blo(u.w); qr[d8 * 8 + 7] = bhi(u.w);
    }
  }

  float mx = -1e30f, l = 0.f;
  float tv[8];
  int ti[8];
#pragma unroll
  for (int j = 0; j < 8; ++j) { tv[j] = -1e30f; ti[j] = 0; }

  for (int t = 0; t < 128; ++t) {
    float s0 = 0.f, s1 = 0.f, s2 = 0.f, s3 = 0.f;
#pragma unroll
    for (int d = 0; d < 64; d += 4) {
      float4 kv = *(const float4*)&ks_[t][d];
      s0 = fmaf(qr[d], kv.x, s0);
      s1 = fmaf(qr[d + 1], kv.y, s1);
      s2 = fmaf(qr[d + 2], kv.z, s2);
      s3 = fmaf(qr[d + 3], kv.w, s3);
    }
    float s = ((s0 + s1) + (s2 + s3)) * 0.125f;
    float mnew = fmaxf(mx, s);
    l = l * __expf(mx - mnew) + __expf(s - mnew);
    mx = mnew;
    // strict > keeps lower index on ties (jax top_k semantics)
    float cv = s;
    int ci = t;
#pragma unroll
    for (int j = 0; j < 8; ++j) {
      bool gt = cv > tv[j];
      float ov = tv[j]; int oi = ti[j];
      tv[j] = gt ? cv : ov; ti[j] = gt ? ci : oi;
      cv = gt ? ov : cv;  ci = gt ? oi : ci;
    }
  }

  if (active) {
    float oacc[64];
#pragma unroll
    for (int d = 0; d < 64; ++d) oacc[d] = 0.f;
    const float invl = 1.f / l;  // denominator over ALL keys (mask applied post-softmax)
#pragma unroll
    for (int j = 0; j < 8; ++j) {
      float p = __expf(tv[j] - mx) * invl;
      int t = ti[j];
#pragma unroll
      for (int d8 = 0; d8 < 8; ++d8) {
        uint4 u = *(const uint4*)&vs[t][d8 * 8];
        oacc[d8 * 8 + 0] = fmaf(p, blo(u.x), oacc[d8 * 8 + 0]);
        oacc[d8 * 8 + 1] = fmaf(p, bhi(u.x), oacc[d8 * 8 + 1]);
        oacc[d8 * 8 + 2] = fmaf(p, blo(u.y), oacc[d8 * 8 + 2]);
        oacc[d8 * 8 + 3] = fmaf(p, bhi(u.y), oacc[d8 * 8 + 3]);
        oacc[d8 * 8 + 4] = fmaf(p, blo(u.z), oacc[d8 * 8 + 4]);
        oacc[d8 * 8 + 5] = fmaf(p, bhi(u.z), oacc[d8 * 8 + 5]);
        oacc[d8 * 8 + 6] = fmaf(p, blo(u.w), oacc[d8 * 8 + 6]);
        oacc[d8 * 8 + 7] = fmaf(p, bhi(u.w), oacc[d8 * 8 + 7]);
      }
    }
    u32* orow = (u32*)(o + (size_t)(b * 1290 + m) * 512 + h * 64);
#pragma unroll
    for (int d2 = 0; d2 < 32; ++d2) orow[d2] = pack2(oacc[2 * d2], oacc[2 * d2 + 1]);
  }
}

// ---------------- attention 2 partials: 128 queries (inp), 1290 keys (next_memory) ----------
__global__ __launch_bounds__(128, 2) void attn2_partial(const u16* __restrict__ q2,
                                                        const u16* __restrict__ k2,
                                                        const u16* __restrict__ v2,
                                                        float* __restrict__ pacc,
                                                        float* __restrict__ pml) {
  __shared__ __align__(16) float kt[64][64];
  __shared__ __align__(16) float vt[64][64];
  const int tid = threadIdx.x;
  const int bh = blockIdx.x;
  const int b = bh >> 3, h = bh & 7;
  const int part = blockIdx.y;
  const int kstart = (part * 1290) >> 2;
  const int kend = ((part + 1) * 1290) >> 2;

  float qr[64];
  {
    const u16* qrow = q2 + (size_t)(b * 128 + tid) * 512 + h * 64;
#pragma unroll
    for (int d8 = 0; d8 < 8; ++d8) {
      uint4 u = *(const uint4*)(qrow + d8 * 8);
      qr[d8 * 8 + 0] = blo(u.x); qr[d8 * 8 + 1] = bhi(u.x);
      qr[d8 * 8 + 2] = blo(u.y); qr[d8 * 8 + 3] = bhi(u.y);
      qr[d8 * 8 + 4] = blo(u.z); qr[d8 * 8 + 5] = bhi(u.z);
      qr[d8 * 8 + 6] = blo(u.w); qr[d8 * 8 + 7] = bhi(u.w);
    }
  }

  float mx = -1e30f, l = 0.f, acc[64];
#pragma unroll
  for (int d = 0; d < 64; ++d) acc[d] = 0.f;

  for (int kb0 = kstart; kb0 < kend; kb0 += 64) {
    int cnt = min(64, kend - kb0);
    __syncthreads();
    for (int i = tid; i < cnt * 64; i += 128) {
      int t = i >> 6, d = i & 63;
      size_t gidx = (size_t)(b * 1290 + kb0 + t) * 512 + h * 64 + d;
      kt[t][d] = b2f(k2[gidx]);
      vt[t][d] = b2f(v2[gidx]);
    }
    __syncthreads();
    for (int t = 0; t < cnt; ++t) {
      float s0 = 0.f, s1 = 0.f, s2 = 0.f, s3 = 0.f;
#pragma unroll
      for (int d = 0; d < 64; d += 4) {
        float4 kv = *(const float4*)&kt[t][d];
        s0 = fmaf(qr[d], kv.x, s0);
        s1 = fmaf(qr[d + 1], kv.y, s1);
        s2 = fmaf(qr[d + 2], kv.z, s2);
        s3 = fmaf(qr[d + 3], kv.w, s3);
      }
      float s = ((s0 + s1) + (s2 + s3)) * 0.125f;
      float mnew = fmaxf(mx, s);
      if (mnew > mx) {
        float a = __expf(mx - mnew);
        l *= a;
#pragma unroll
        for (int d = 0; d < 64; ++d) acc[d] *= a;
        mx = mnew;
      }
      float p = __expf(s - mx);
      l += p;
#pragma unroll
      for (int d = 0; d < 64; d += 4) {
        float4 vv = *(const float4*)&vt[t][d];
        acc[d] = fmaf(p, vv.x, acc[d]);
        acc[d + 1] = fmaf(p, vv.y, acc[d + 1]);
        acc[d + 2] = fmaf(p, vv.z, acc[d + 2]);
        acc[d + 3] = fmaf(p, vv.w, acc[d + 3]);
      }
    }
  }
  size_t pi = (size_t)(part * 256 + bh) * 128 + tid;
  float* pa = pacc + pi * 64;
#pragma unroll
  for (int d = 0; d < 64; d += 4)
    *(float4*)(pa + d) = make_float4(acc[d], acc[d + 1], acc[d + 2], acc[d + 3]);
  pml[pi * 2 + 0] = mx;
  pml[pi * 2 + 1] = l;
}

__global__ __launch_bounds__(64) void attn2_merge(const float* __restrict__ pacc,
                                                  const float* __restrict__ pml,
                                                  void* __restrict__ outp,
                                                  const int* __restrict__ flag) {
  const int qi = blockIdx.x;  // bh*128 + t
  const int bh = qi >> 7, t = qi & 127;
  const int b = bh >> 3, h = bh & 7;
  const int lane = threadIdx.x;
  float mv[4], lv[4];
  float m0 = -1e30f;
#pragma unroll
  for (int i = 0; i < 4; ++i) {
    size_t pi = (size_t)(i * 256 + bh) * 128 + t;
    mv[i] = pml[pi * 2];
    lv[i] = pml[pi * 2 + 1];
    m0 = fmaxf(m0, mv[i]);
  }
  float L = 0.f, accd = 0.f;
#pragma unroll
  for (int i = 0; i < 4; ++i) {
    size_t pi = (size_t)(i * 256 + bh) * 128 + t;
    float e = __expf(mv[i] - m0);
    L += lv[i] * e;
    accd += pacc[pi * 64 + lane] * e;
  }
  float v = accd / L;
  size_t off = (size_t)41280 * 512 + ((size_t)(b * 128 + t) * 512 + h * 64 + lane);
  if (*flag) ((float*)outp)[off] = v; else ((u16*)outp)[off] = f2b(v);
}

// ---------------- gates, two passes ----------------
__global__ __launch_bounds__(512) void gatesA_kernel(const u16* __restrict__ gmb,
                                                     const u16* __restrict__ gi,
                                                     const u16* __restrict__ memfin,
                                                     const u16* __restrict__ ibp,
                                                     u16* __restrict__ pnm) {
  const int r = blockIdx.x;
  const int b = r / 1290;
  const int c = threadIdx.x;
  const float ibias = b2f(ibp[0]);
  size_t idx = (size_t)r * 512 + c;
  float ig = sigm(b2f(gmb[idx]) + b2f(gi[b * 1024 + c]) + ibias);
  pnm[idx] = f2b(ig * tanhf(b2f(memfin[idx])));
}

__global__ __launch_bounds__(512) void gatesB_kernel(const u16* __restrict__ gmb,
                                                     const u16* __restrict__ gi,
                                                     const u16* __restrict__ pnm,
                                                     const u16* __restrict__ mem_in,
                                                     const u16* __restrict__ fbp,
                                                     u16* __restrict__ nmbf,
                                                     void* __restrict__ outp,
                                                     const int* __restrict__ flag) {
  const int r = blockIdx.x;
  const int b = r / 1290;
  const int c = threadIdx.x;
  const float fbias = b2f(fbp[0]);
  size_t idx = (size_t)r * 512 + c;
  float fg = sigm(b2f(gmb[idx]) + b2f(gi[b * 1024 + 512 + c]) + fbias);
  float v = b2f(pnm[idx]) + fg * b2f(mem_in[idx]);
  nmbf[idx] = f2b(v);
  if (*flag) ((float*)outp)[idx] = v; else ((u16*)outp)[idx] = f2b(v);
}

extern "C" void kernel_launch(void* const* d_in, const int* in_sizes, int n_in,
                              void* d_out, int out_size, void* d_ws, size_t ws_size,
                              hipStream_t stream) {
  (void)out_size; (void)ws_size;
  char* ws = (char*)d_ws;
  size_t off = 0;
  auto alloc = [&](size_t bytes) {
    char* p = ws + off;
    off += (bytes + 255) & ~(size_t)255;
    return (void*)p;
  };

  int* flag = (int*)alloc(256);

  // bf16 arena for all inputs
  size_t aoffs[32];
  size_t total = 0;
  for (int i = 0; i < n_in; ++i) {
    aoffs[i] = total;
    total += ((size_t)in_sizes[i] + 127) & ~(size_t)127;
  }
  u16* arena = (u16*)alloc(total * 2);

  const u16* c_ipts = arena + aoffs[0];
  const u16* c_mem  = arena + aoffs[1];
  const u16* c_Wq = arena + aoffs[2];  const u16* c_bq = arena + aoffs[3];
  const u16* c_Wk = arena + aoffs[4];  const u16* c_bk = arena + aoffs[5];
  const u16* c_Wv = arena + aoffs[6];  const u16* c_bv = arena + aoffs[7];
  const u16* c_Wm = arena + aoffs[8];  const u16* c_bm = arena + aoffs[9];
  const u16* c_g1 = arena + aoffs[10]; const u16* c_b1 = arena + aoffs[11];
  const u16* c_g2 = arena + aoffs[12]; const u16* c_b2 = arena + aoffs[13];
  const u16* c_Wp = arena + aoffs[14]; const u16* c_bp = arena + aoffs[15];
  const u16* c_repw = arena + aoffs[16];
  const u16* c_Wig = arena + aoffs[17]; const u16* c_big = arena + aoffs[18];
  const u16* c_Wmg = arena + aoffs[19]; const u16* c_bmg = arena + aoffs[20];
  const u16* c_fb = arena + aoffs[21];
  const u16* c_ib = arena + aoffs[22];

  u16* WqT = (u16*)alloc(512 * 512 * 2);
  u16* WkT = (u16*)alloc(512 * 512 * 2);
  u16* WvT = (u16*)alloc(512 * 512 * 2);
  u16* WmT = (u16*)alloc(512 * 512 * 2);
  u16* WpT = (u16*)alloc(512 * 512 * 2);
  u16* WigT = (u16*)alloc(512 * 1024 * 2);
  u16* WmgT = (u16*)alloc(512 * 1024 * 2);
  u16* inp = (u16*)alloc((size_t)4096 * 512 * 2);
  u16* kbase = (u16*)alloc((size_t)4096 * 512 * 2);
  u16* vbase = (u16*)alloc((size_t)4096 * 512 * 2);
  u16* q2 = (u16*)alloc((size_t)4096 * 512 * 2);
  u16* rmean = (u16*)alloc(32 * 512 * 2);
  u16* gi = (u16*)alloc(32 * 1024 * 2);
  u16* membf = (u16*)alloc((size_t)41280 * 512 * 2);
  u16* qbuf = (u16*)alloc((size_t)41280 * 512 * 2);
  u16* obuf = (u16*)alloc((size_t)41280 * 512 * 2);
  u16* gmbuf = (u16*)alloc((size_t)41280 * 512 * 2);
  u16* nmbf = (u16*)alloc((size_t)41280 * 512 * 2);
  // attn2 partials alias gmbuf (dead after gatesB): 32MB pacc + 1MB pml <= 42.3MB
  float* pacc = (float*)(void*)gmbuf;
  float* pml = (float*)((char*)(void*)gmbuf + (size_t)4 * 32768 * 64 * 4);

  // 0. dtype detect + convert everything to bf16 arena
  detect_kernel<<<1, 64, 0, stream>>>((const u16*)d_in[0], flag);
  for (int i = 0; i < n_in; ++i) {
    int n = in_sizes[i];
    convert_kernel<<<(n + 255) / 256, 256, 0, stream>>>(d_in[i], arena + aoffs[i], n, flag);
  }

  // 1. transpose all weights to [N,K]
  transpose_kernel<<<dim3(16, 16), 256, 0, stream>>>(c_Wq, WqT, 512, 512);
  transpose_kernel<<<dim3(16, 16), 256, 0, stream>>>(c_Wk, WkT, 512, 512);
  transpose_kernel<<<dim3(16, 16), 256, 0, stream>>>(c_Wv, WvT, 512, 512);
  transpose_kernel<<<dim3(16, 16), 256, 0, stream>>>(c_Wm, WmT, 512, 512);
  transpose_kernel<<<dim3(16, 16), 256, 0, stream>>>(c_Wp, WpT, 512, 512);
  transpose_kernel<<<dim3(32, 16), 256, 0, stream>>>(c_Wig, WigT, 512, 1024);
  transpose_kernel<<<dim3(32, 16), 256, 0, stream>>>(c_Wmg, WmgT, 512, 1024);

  // 2. projections of ipts (loop-invariant)
  gemm_bt<0><<<dim3(32, 4), 256, 0, stream>>>(c_ipts, WpT, c_bp, inp, 4096, 512);
  gemm_bt<0><<<dim3(32, 4), 256, 0, stream>>>(inp, WkT, c_bk, kbase, 4096, 512);
  gemm_bt<0><<<dim3(32, 4), 256, 0, stream>>>(inp, WvT, c_bv, vbase, 4096, 512);
  gemm_bt<0><<<dim3(32, 4), 256, 0, stream>>>(inp, WqT, c_bq, q2, 4096, 512);

  // 3. input gate term gi
  redmean_kernel<<<dim3(32, 2), 256, 0, stream>>>(inp, c_repw, rmean);
  gemm_bt<0><<<dim3(1, 8), 256, 0, stream>>>(rmean, WigT, c_big, gi, 32, 1024);

  // 4. the 4 relational blocks
  const u16* memsrc = c_mem;
  for (int it = 0; it < 4; ++it) {
    gemm_bt<0><<<dim3(323, 4), 256, 0, stream>>>(memsrc, WqT, c_bq, qbuf, 41280, 512);
    attn1_kernel<<<dim3(6, 256), 256, 0, stream>>>(qbuf, kbase, vbase, obuf);
    ln_kernel<<<dim3(41280), 64, 0, stream>>>(memsrc, obuf, membf, c_g1, c_b1);
    gemm_bt<1><<<dim3(323, 4), 256, 0, stream>>>(membf, WmT, c_bm, qbuf, 41280, 512);
    gemm_bt<1><<<dim3(323, 4), 256, 0, stream>>>(qbuf, WmT, c_bm, obuf, 41280, 512);
    ln_kernel<<<dim3(41280), 64, 0, stream>>>(membf, obuf, membf, c_g2, c_b2);
    memsrc = membf;
  }

  // 5. gates in two passes (gm split by output-column half; qbuf free -> tanh(memory))
  tanhmem_kernel<<<dim3(2641920 / 256), 256, 0, stream>>>(c_mem, qbuf, 2641920);
  gemm_bt<0><<<dim3(323, 4), 256, 0, stream>>>(qbuf, WmgT, c_bmg, gmbuf, 41280, 512);
  gatesA_kernel<<<dim3(41280), 512, 0, stream>>>(gmbuf, gi, membf, c_ib, nmbf);
  gemm_bt<0><<<dim3(323, 4), 256, 0, stream>>>(qbuf, WmgT + (size_t)512 * 512, c_bmg + 512, gmbuf, 41280, 512);
  gatesB_kernel<<<dim3(41280), 512, 0, stream>>>(gmbuf, gi, nmbf, c_mem, c_fb, nmbf, d_out, flag);

  // 6. hx attention: q from inp, k/v from next_memory (output 1)
  gemm_bt<0><<<dim3(323, 4), 256, 0, stream>>>(nmbf, WkT, c_bk, qbuf, 41280, 512);
  gemm_bt<0><<<dim3(323, 4), 256, 0, stream>>>(nmbf, WvT, c_bv, obuf, 41280, 512);
  attn2_partial<<<dim3(256, 4), 128, 0, stream>>>(q2, qbuf, obuf, pacc, pml);
  attn2_merge<<<dim3(32768), 64, 0, stream>>>(pacc, pml, d_out, flag);
}

// Round 3
// 2926.732 us; speedup vs baseline: 1.4980x; 1.4980x over previous
//
#include <hip/hip_runtime.h>
#include <stdint.h>

typedef uint16_t u16;
typedef uint32_t u32;

#define DEVI __device__ __forceinline__

DEVI float b2f(u16 u) { return __uint_as_float(((u32)u) << 16); }
DEVI float blo(u32 u) { return __uint_as_float(u << 16); }
DEVI float bhi(u32 u) { return __uint_as_float(u & 0xffff0000u); }
DEVI u16 f2b(float f) {
  u32 x = __float_as_uint(f);
  return (u16)((x + 0x7fffu + ((x >> 16) & 1u)) >> 16);
}
DEVI u32 pack2(float a, float b) { return (u32)f2b(a) | ((u32)f2b(b) << 16); }
DEVI float sigm(float x) { return 1.f / (1.f + __expf(-x)); }

typedef __bf16 bf16x8 __attribute__((ext_vector_type(8)));
typedef float f32x4 __attribute__((ext_vector_type(4)));

DEVI void gll16(const void* g, void* l) {
  __builtin_amdgcn_global_load_lds((const __attribute__((address_space(1))) void*)g,
                                   (__attribute__((address_space(3))) void*)l, 16, 0, 0);
}

// ---------------- input dtype detect: 0 = bf16, 1 = fp32 ----------------
__global__ void detect_kernel(const u16* __restrict__ x, int* __restrict__ flag) {
  if (threadIdx.x == 0 && blockIdx.x == 0) {
    int f = 0;
    for (int i = 0; i < 64; ++i) {
      u16 u = x[2 * i];  // low half if fp32
      int e = (u >> 7) & 0xFF;
      if (e > 131) f = 1;  // |val| >= 32 impossible for randn bf16
    }
    *flag = f;
  }
}

// ---------------- fused convert: all inputs -> bf16 arena, one dispatch ----------------
struct CvtArgs {
  const void* src[23];
  int aoff[23];  // arena element offset (monotone)
  int n[23];     // element count
  int total;     // padded arena elements (multiple of 4)
};

__global__ __launch_bounds__(256) void convert_fused(CvtArgs a, u16* __restrict__ arena,
                                                     const int* __restrict__ flag) {
  int e4 = (blockIdx.x * 256 + threadIdx.x) * 4;
  if (e4 >= a.total) return;
  const char* sp = (const char*)a.src[0];
  int rel = e4, cnt = a.n[0];
#pragma unroll
  for (int j = 1; j < 23; ++j)
    if (e4 >= a.aoff[j]) { sp = (const char*)a.src[j]; rel = e4 - a.aoff[j]; cnt = a.n[j]; }
  const bool f32 = (*flag != 0);
  if (rel + 3 < cnt) {
    if (f32) {
      float4 v = *(const float4*)(sp + (size_t)rel * 4);
      uint2 o;
      o.x = pack2(v.x, v.y);
      o.y = pack2(v.z, v.w);
      *(uint2*)(arena + e4) = o;
    } else {
      *(uint2*)(arena + e4) = *(const uint2*)(sp + (size_t)rel * 2);
    }
  } else {
#pragma unroll
    for (int k = 0; k < 4; ++k) {
      u16 o = 0;
      if (rel + k < cnt)
        o = f32 ? f2b(((const float*)sp)[rel + k]) : ((const u16*)sp)[rel + k];
      arena[e4 + k] = o;
    }
  }
}

// ---------------- GEMM: C[m,n] = act(A[m,:] . Bt[n,:] + bias[n]) -> bf16 ----------------
// m97 pattern: 128x128 tile, BK=64, 256 threads, global_load_lds width=16,
// XOR-swizzled LDS (16B chunk slot s = kchunk ^ (row&7)) for conflict-free ds_read_b128.
template <int ACT>
__global__ __launch_bounds__(256, 3) void gemm_bt(
    const u16* __restrict__ A, const u16* __restrict__ Bt,
    const u16* __restrict__ bias, u16* __restrict__ Co, int Mtot, int Ntot) {
  __shared__ __align__(16) u16 aT[128 * 64];
  __shared__ __align__(16) u16 bT[128 * 64];
  const int tid = threadIdx.x;
  const int lane = tid & 63;
  const int w = tid >> 6;
  const int m0 = blockIdx.x * 128;
  const int n0 = blockIdx.y * 128;
  const int wm = (w & 1) << 6;
  const int wn = (w >> 1) << 6;

  f32x4 acc[4][4] = {};

  const u16* ga[4];
  const u16* gb[4];
#pragma unroll
  for (int q = 0; q < 4; ++q) {
    int j = q * 256 + tid;
    int r = j >> 3, s = j & 7;
    int c = (s ^ (r & 7)) * 8;  // swizzle folded into global column
    int ra = m0 + r;
    if (ra >= Mtot) ra = Mtot - 1;
    ga[q] = A + (size_t)ra * 512 + c;
    gb[q] = Bt + (size_t)(n0 + r) * 512 + c;
  }

  for (int ko = 0; ko < 8; ++ko) {
    const int k0 = ko * 64;
#pragma unroll
    for (int q = 0; q < 4; ++q) {
      int j = q * 256 + tid;
      gll16(ga[q] + k0, aT + j * 8);
      gll16(gb[q] + k0, bT + j * 8);
    }
    __syncthreads();
#pragma unroll
    for (int ks = 0; ks < 2; ++ks) {
      bf16x8 af[4], bfr[4];
#pragma unroll
      for (int i = 0; i < 4; ++i) {
        int cch = ks * 4 + (lane >> 4);
        int r = wm + i * 16 + (lane & 15);
        af[i] = *(const bf16x8*)(aT + (r * 8 + (cch ^ (r & 7))) * 8);
        int rn = wn + i * 16 + (lane & 15);
        bfr[i] = *(const bf16x8*)(bT + (rn * 8 + (cch ^ (rn & 7))) * 8);
      }
#pragma unroll
      for (int i = 0; i < 4; ++i)
#pragma unroll
        for (int jn = 0; jn < 4; ++jn)
          acc[i][jn] = __builtin_amdgcn_mfma_f32_16x16x32_bf16(af[i], bfr[jn], acc[i][jn], 0, 0, 0);
    }
    __syncthreads();
  }

  const int cl = lane & 15;
  const int rg = lane >> 4;
#pragma unroll
  for (int jn = 0; jn < 4; ++jn) {
    int col = n0 + wn + jn * 16 + cl;
    float bv = b2f(bias[col]);
#pragma unroll
    for (int i = 0; i < 4; ++i) {
      int rowb = m0 + wm + i * 16 + rg * 4;
#pragma unroll
      for (int rr = 0; rr < 4; ++rr) {
        int row = rowb + rr;
        if (row < Mtot) {
          float vv = acc[i][jn][rr] + bv;
          if (ACT) vv = fmaxf(vv, 0.f);
          Co[(size_t)row * Ntot + col] = f2b(vv);
        }
      }
    }
  }
}

// ---------------- weight transpose [K,N] bf16 -> [N,K] bf16 ----------------
__global__ __launch_bounds__(256) void transpose_kernel(const u16* __restrict__ in,
                                                        u16* __restrict__ outb, int K, int N) {
  __shared__ u16 tile[32][33];
  const int tx = threadIdx.x & 31, ty = threadIdx.x >> 5;
  const int bx = blockIdx.x * 32;  // N dim
  const int by = blockIdx.y * 32;  // K dim
#pragma unroll
  for (int i = 0; i < 32; i += 8) tile[ty + i][tx] = in[(size_t)(by + ty + i) * N + bx + tx];
  __syncthreads();
#pragma unroll
  for (int i = 0; i < 32; i += 8) outb[(size_t)(bx + ty + i) * K + by + tx] = tile[tx][ty + i];
}

// ---------------- tanh(memory) -> bf16 ----------------
__global__ void tanhmem_kernel(const u16* __restrict__ mi, u16* __restrict__ th, int n8) {
  int i = blockIdx.x * 256 + threadIdx.x;
  if (i >= n8) return;
  uint4 u = ((const uint4*)mi)[i];
  uint4 t;
  t.x = pack2(tanhf(blo(u.x)), tanhf(bhi(u.x)));
  t.y = pack2(tanhf(blo(u.y)), tanhf(bhi(u.y)));
  t.z = pack2(tanhf(blo(u.z)), tanhf(bhi(u.z)));
  t.w = pack2(tanhf(blo(u.w)), tanhf(bhi(u.w)));
  ((uint4*)th)[i] = t;
}

// ---------------- rmean[b,c] = mean_t relu(rep_w[c] * inp[b,t,c]) ----------------
__global__ void redmean_kernel(const u16* __restrict__ inp, const u16* __restrict__ repw,
                               u16* __restrict__ outb) {
  const int b = blockIdx.x;
  const int c = blockIdx.y * 256 + threadIdx.x;
  const float rw = b2f(repw[c]);
  float s = 0.f;
  for (int t = 0; t < 128; ++t)
    s += fmaxf(rw * b2f(inp[(size_t)(b * 128 + t) * 512 + c]), 0.f);
  outb[b * 512 + c] = f2b(s * (1.f / 128.f));
}

// ---------------- LayerNorm(src + add) -> dst ----------------
__global__ __launch_bounds__(64) void ln_kernel(const u16* __restrict__ src,
                                                const u16* __restrict__ addb,
                                                u16* __restrict__ dst,
                                                const u16* __restrict__ g,
                                                const u16* __restrict__ bb) {
  const int row = blockIdx.x;
  const int lane = threadIdx.x;
  const u16* srow = src + (size_t)row * 512;
  const u16* arow = addb + (size_t)row * 512;
  float x[8];
  float s = 0.f;
#pragma unroll
  for (int i = 0; i < 8; ++i) {
    int c = lane + i * 64;
    x[i] = b2f(srow[c]) + b2f(arow[c]);
    s += x[i];
  }
#pragma unroll
  for (int off = 32; off > 0; off >>= 1) s += __shfl_xor(s, off, 64);
  const float mu = s * (1.f / 512.f);
  float v = 0.f;
#pragma unroll
  for (int i = 0; i < 8; ++i) {
    float d = x[i] - mu;
    v = fmaf(d, d, v);
  }
#pragma unroll
  for (int off = 32; off > 0; off >>= 1) v += __shfl_xor(v, off, 64);
  const float rstd = rsqrtf(v * (1.f / 512.f) + 1e-5f);
  u16* orow = dst + (size_t)row * 512;
#pragma unroll
  for (int i = 0; i < 8; ++i) {
    int c = lane + i * 64;
    orow[c] = f2b(fmaf((x[i] - mu) * rstd, b2f(g[c]), b2f(bb[c])));
  }
}

// ---------------- attention 1: 1290 queries (mem), 128 keys (inp), top-8 mask ----------------
// K rows are wave-uniform per key iteration -> scalar (SMEM) loads + SALU bf16 unpack;
// V stays in LDS (divergent top-8 gather), bank-spread via 72-u16 row pad.
__global__ __launch_bounds__(256, 2) void attn1_kernel(const u16* __restrict__ q,
                                                       const u16* __restrict__ kb,
                                                       const u16* __restrict__ vb,
                                                       u16* __restrict__ o) {
  __shared__ __align__(16) u16 vs[128][72];
  const int tid = threadIdx.x;
  const int bh = blockIdx.y;
  const int b = bh >> 3, h = bh & 7;

  for (int i = tid; i < 128 * 8; i += 256) {
    int t = i >> 3, d8 = i & 7;
    uint4 u = *(const uint4*)(vb + (size_t)(b * 128 + t) * 512 + h * 64 + d8 * 8);
    *(uint4*)&vs[t][d8 * 8] = u;
  }
  __syncthreads();

  const int m = blockIdx.x * 256 + tid;
  const bool active = (m < 1290);
  const int mm = active ? m : 0;

  float qr[64];
  {
    const u16* qrow = q + (size_t)(b * 1290 + mm) * 512 + h * 64;
#pragma unroll
    for (int d8 = 0; d8 < 8; ++d8) {
      uint4 u = *(const uint4*)(qrow + d8 * 8);
      qr[d8 * 8 + 0] = blo(u.x); qr[d8 * 8 + 1] = bhi(u.x);
      qr[d8 * 8 + 2] = blo(u.y); qr[d8 * 8 + 3] = bhi(u.y);
      qr[d8 * 8 + 4] = blo(u.z); qr[d8 * 8 + 5] = bhi(u.z);
      qr[d8 * 8 + 6] = blo(u.w); qr[d8 * 8 + 7] = bhi(u.w);
    }
  }

  float mx = -1e30f, l = 0.f;
  float tv[8];
  int ti[8];
#pragma unroll
  for (int j = 0; j < 8; ++j) { tv[j] = -1e30f; ti[j] = 0; }

  const u32* kbh = (const u32*)(kb + (size_t)(b * 128) * 512 + h * 64);
  for (int t = 0; t < 128; ++t) {
    const u32* krow = kbh + (size_t)t * 256;  // uniform address -> s_load
    float s0 = 0.f, s1 = 0.f, s2 = 0.f, s3 = 0.f;
#pragma unroll
    for (int d2 = 0; d2 < 32; d2 += 2) {
      u32 p0 = krow[d2], p1 = krow[d2 + 1];
      s0 = fmaf(qr[2 * d2 + 0], blo(p0), s0);
      s1 = fmaf(qr[2 * d2 + 1], bhi(p0), s1);
      s2 = fmaf(qr[2 * d2 + 2], blo(p1), s2);
      s3 = fmaf(qr[2 * d2 + 3], bhi(p1), s3);
    }
    float s = ((s0 + s1) + (s2 + s3)) * 0.125f;
    float mnew = fmaxf(mx, s);
    l = l * __expf(mx - mnew) + __expf(s - mnew);
    mx = mnew;
    // strict > keeps lower index on ties (jax top_k); skip when s can't enter list
    if (s > tv[7]) {
      float cv = s;
      int ci = t;
#pragma unroll
      for (int j = 0; j < 8; ++j) {
        bool gt = cv > tv[j];
        float ov = tv[j]; int oi = ti[j];
        tv[j] = gt ? cv : ov; ti[j] = gt ? ci : oi;
        cv = gt ? ov : cv;  ci = gt ? oi : ci;
      }
    }
  }

  if (active) {
    float oacc[64];
#pragma unroll
    for (int d = 0; d < 64; ++d) oacc[d] = 0.f;
    const float invl = 1.f / l;  // denominator over ALL keys (mask applied post-softmax)
#pragma unroll
    for (int j = 0; j < 8; ++j) {
      float p = __expf(tv[j] - mx) * invl;
      int t = ti[j];
#pragma unroll
      for (int d8 = 0; d8 < 8; ++d8) {
        uint4 u = *(const uint4*)&vs[t][d8 * 8];
        oacc[d8 * 8 + 0] = fmaf(p, blo(u.x), oacc[d8 * 8 + 0]);
        oacc[d8 * 8 + 1] = fmaf(p, bhi(u.x), oacc[d8 * 8 + 1]);
        oacc[d8 * 8 + 2] = fmaf(p, blo(u.y), oacc[d8 * 8 + 2]);
        oacc[d8 * 8 + 3] = fmaf(p, bhi(u.y), oacc[d8 * 8 + 3]);
        oacc[d8 * 8 + 4] = fmaf(p, blo(u.z), oacc[d8 * 8 + 4]);
        oacc[d8 * 8 + 5] = fmaf(p, bhi(u.z), oacc[d8 * 8 + 5]);
        oacc[d8 * 8 + 6] = fmaf(p, blo(u.w), oacc[d8 * 8 + 6]);
        oacc[d8 * 8 + 7] = fmaf(p, bhi(u.w), oacc[d8 * 8 + 7]);
      }
    }
    u32* orow = (u32*)(o + (size_t)(b * 1290 + m) * 512 + h * 64);
#pragma unroll
    for (int d2 = 0; d2 < 32; ++d2) orow[d2] = pack2(oacc[2 * d2], oacc[2 * d2 + 1]);
  }
}

// ---------------- attention 2 partials: 128 q (inp), 1290 k (next_memory), 4-way key split --
// No LDS: K/V rows wave-uniform -> scalar loads + SALU unpack; VALU does only the FMAs.
__global__ __launch_bounds__(128, 2) void attn2_partial(const u16* __restrict__ q2,
                                                        const u16* __restrict__ k2,
                                                        const u16* __restrict__ v2,
                                                        float* __restrict__ pacc,
                                                        float* __restrict__ pml) {
  const int tid = threadIdx.x;
  const int bh = blockIdx.x;
  const int b = bh >> 3, h = bh & 7;
  const int part = blockIdx.y;
  const int kstart = (part * 1290) >> 2;
  const int kend = ((part + 1) * 1290) >> 2;

  float qr[64];
  {
    const u16* qrow = q2 + (size_t)(b * 128 + tid) * 512 + h * 64;
#pragma unroll
    for (int d8 = 0; d8 < 8; ++d8) {
      uint4 u = *(const uint4*)(qrow + d8 * 8);
      qr[d8 * 8 + 0] = blo(u.x); qr[d8 * 8 + 1] = bhi(u.x);
      qr[d8 * 8 + 2] = blo(u.y); qr[d8 * 8 + 3] = bhi(u.y);
      qr[d8 * 8 + 4] = blo(u.z); qr[d8 * 8 + 5] = bhi(u.z);
      qr[d8 * 8 + 6] = blo(u.w); qr[d8 * 8 + 7] = bhi(u.w);
    }
  }

  float mx = -1e30f, l = 0.f, acc[64];
#pragma unroll
  for (int d = 0; d < 64; ++d) acc[d] = 0.f;

  const u32* kbh = (const u32*)(k2 + (size_t)(b * 1290) * 512 + h * 64);
  const u32* vbh = (const u32*)(v2 + (size_t)(b * 1290) * 512 + h * 64);
  for (int t = kstart; t < kend; ++t) {
    const u32* krow = kbh + (size_t)t * 256;  // uniform -> s_load
    const u32* vrow = vbh + (size_t)t * 256;
    float s0 = 0.f, s1 = 0.f, s2 = 0.f, s3 = 0.f;
#pragma unroll
    for (int d2 = 0; d2 < 32; d2 += 2) {
      u32 p0 = krow[d2], p1 = krow[d2 + 1];
      s0 = fmaf(qr[2 * d2 + 0], blo(p0), s0);
      s1 = fmaf(qr[2 * d2 + 1], bhi(p0), s1);
      s2 = fmaf(qr[2 * d2 + 2], blo(p1), s2);
      s3 = fmaf(qr[2 * d2 + 3], bhi(p1), s3);
    }
    float s = ((s0 + s1) + (s2 + s3)) * 0.125f;
    float mnew = fmaxf(mx, s);
    if (mnew > mx) {  // rare after warm-up; exec-masked rescale
      float a = __expf(mx - mnew);
      l *= a;
#pragma unroll
      for (int d = 0; d < 64; ++d) acc[d] *= a;
      mx = mnew;
    }
    float p = __expf(s - mx);
    l += p;
#pragma unroll
    for (int d2 = 0; d2 < 32; d2 += 2) {
      u32 v0 = vrow[d2], v1 = vrow[d2 + 1];
      acc[2 * d2 + 0] = fmaf(p, blo(v0), acc[2 * d2 + 0]);
      acc[2 * d2 + 1] = fmaf(p, bhi(v0), acc[2 * d2 + 1]);
      acc[2 * d2 + 2] = fmaf(p, blo(v1), acc[2 * d2 + 2]);
      acc[2 * d2 + 3] = fmaf(p, bhi(v1), acc[2 * d2 + 3]);
    }
  }
  size_t pi = (size_t)(part * 256 + bh) * 128 + tid;
  float* pa = pacc + pi * 64;
#pragma unroll
  for (int d = 0; d < 64; d += 4)
    *(float4*)(pa + d) = make_float4(acc[d], acc[d + 1], acc[d + 2], acc[d + 3]);
  pml[pi * 2 + 0] = mx;
  pml[pi * 2 + 1] = l;
}

__global__ __launch_bounds__(64) void attn2_merge(const float* __restrict__ pacc,
                                                  const float* __restrict__ pml,
                                                  void* __restrict__ outp,
                                                  const int* __restrict__ flag) {
  const int qi = blockIdx.x;  // bh*128 + t
  const int bh = qi >> 7, t = qi & 127;
  const int b = bh >> 3, h = bh & 7;
  const int lane = threadIdx.x;
  float mv[4], lv[4];
  float m0 = -1e30f;
#pragma unroll
  for (int i = 0; i < 4; ++i) {
    size_t pi = (size_t)(i * 256 + bh) * 128 + t;
    mv[i] = pml[pi * 2];
    lv[i] = pml[pi * 2 + 1];
    m0 = fmaxf(m0, mv[i]);
  }
  float L = 0.f, accd = 0.f;
#pragma unroll
  for (int i = 0; i < 4; ++i) {
    size_t pi = (size_t)(i * 256 + bh) * 128 + t;
    float e = __expf(mv[i] - m0);
    L += lv[i] * e;
    accd += pacc[pi * 64 + lane] * e;
  }
  float v = accd / L;
  size_t off = (size_t)41280 * 512 + ((size_t)(b * 128 + t) * 512 + h * 64 + lane);
  if (*flag) ((float*)outp)[off] = v; else ((u16*)outp)[off] = f2b(v);
}

// ---------------- gates, two passes ----------------
__global__ __launch_bounds__(512) void gatesA_kernel(const u16* __restrict__ gmb,
                                                     const u16* __restrict__ gi,
                                                     const u16* __restrict__ memfin,
                                                     const u16* __restrict__ ibp,
                                                     u16* __restrict__ pnm) {
  const int r = blockIdx.x;
  const int b = r / 1290;
  const int c = threadIdx.x;
  const float ibias = b2f(ibp[0]);
  size_t idx = (size_t)r * 512 + c;
  float ig = sigm(b2f(gmb[idx]) + b2f(gi[b * 1024 + c]) + ibias);
  pnm[idx] = f2b(ig * tanhf(b2f(memfin[idx])));
}

__global__ __launch_bounds__(512) void gatesB_kernel(const u16* __restrict__ gmb,
                                                     const u16* __restrict__ gi,
                                                     const u16* __restrict__ pnm,
                                                     const u16* __restrict__ mem_in,
                                                     const u16* __restrict__ fbp,
                                                     u16* __restrict__ nmbf,
                                                     void* __restrict__ outp,
                                                     const int* __restrict__ flag) {
  const int r = blockIdx.x;
  const int b = r / 1290;
  const int c = threadIdx.x;
  const float fbias = b2f(fbp[0]);
  size_t idx = (size_t)r * 512 + c;
  float fg = sigm(b2f(gmb[idx]) + b2f(gi[b * 1024 + 512 + c]) + fbias);
  float v = b2f(pnm[idx]) + fg * b2f(mem_in[idx]);
  nmbf[idx] = f2b(v);
  if (*flag) ((float*)outp)[idx] = v; else ((u16*)outp)[idx] = f2b(v);
}

extern "C" void kernel_launch(void* const* d_in, const int* in_sizes, int n_in,
                              void* d_out, int out_size, void* d_ws, size_t ws_size,
                              hipStream_t stream) {
  (void)out_size; (void)ws_size;
  char* ws = (char*)d_ws;
  size_t off = 0;
  auto alloc = [&](size_t bytes) {
    char* p = ws + off;
    off += (bytes + 255) & ~(size_t)255;
    return (void*)p;
  };

  int* flag = (int*)alloc(256);

  // bf16 arena for all inputs
  size_t aoffs[32];
  size_t total = 0;
  for (int i = 0; i < n_in; ++i) {
    aoffs[i] = total;
    total += ((size_t)in_sizes[i] + 127) & ~(size_t)127;
  }
  u16* arena = (u16*)alloc(total * 2);

  const u16* c_ipts = arena + aoffs[0];
  const u16* c_mem  = arena + aoffs[1];
  const u16* c_bq = arena + aoffs[3];
  const u16* c_Wq = arena + aoffs[2];
  const u16* c_Wk = arena + aoffs[4];  const u16* c_bk = arena + aoffs[5];
  const u16* c_Wv = arena + aoffs[6];  const u16* c_bv = arena + aoffs[7];
  const u16* c_Wm = arena + aoffs[8];  const u16* c_bm = arena + aoffs[9];
  const u16* c_g1 = arena + aoffs[10]; const u16* c_b1 = arena + aoffs[11];
  const u16* c_g2 = arena + aoffs[12]; const u16* c_b2 = arena + aoffs[13];
  const u16* c_Wp = arena + aoffs[14]; const u16* c_bp = arena + aoffs[15];
  const u16* c_repw = arena + aoffs[16];
  const u16* c_Wig = arena + aoffs[17]; const u16* c_big = arena + aoffs[18];
  const u16* c_Wmg = arena + aoffs[19]; const u16* c_bmg = arena + aoffs[20];
  const u16* c_fb = arena + aoffs[21];
  const u16* c_ib = arena + aoffs[22];

  u16* WqT = (u16*)alloc(512 * 512 * 2);
  u16* WkT = (u16*)alloc(512 * 512 * 2);
  u16* WvT = (u16*)alloc(512 * 512 * 2);
  u16* WmT = (u16*)alloc(512 * 512 * 2);
  u16* WpT = (u16*)alloc(512 * 512 * 2);
  u16* WigT = (u16*)alloc(512 * 1024 * 2);
  u16* WmgT = (u16*)alloc(512 * 1024 * 2);
  u16* inp = (u16*)alloc((size_t)4096 * 512 * 2);
  u16* kbase = (u16*)alloc((size_t)4096 * 512 * 2);
  u16* vbase = (u16*)alloc((size_t)4096 * 512 * 2);
  u16* q2 = (u16*)alloc((size_t)4096 * 512 * 2);
  u16* rmean = (u16*)alloc(32 * 512 * 2);
  u16* gi = (u16*)alloc(32 * 1024 * 2);
  u16* membf = (u16*)alloc((size_t)41280 * 512 * 2);
  u16* qbuf = (u16*)alloc((size_t)41280 * 512 * 2);
  u16* obuf = (u16*)alloc((size_t)41280 * 512 * 2);
  u16* gmbuf = (u16*)alloc((size_t)41280 * 512 * 2);
  u16* nmbf = (u16*)alloc((size_t)41280 * 512 * 2);
  // attn2 partials alias gmbuf (dead after gatesB): 33.6MB pacc + 1MB pml <= 42.3MB
  float* pacc = (float*)(void*)gmbuf;
  float* pml = (float*)((char*)(void*)gmbuf + (size_t)4 * 32768 * 64 * 4);

  // 0. dtype detect + single fused convert into bf16 arena
  detect_kernel<<<1, 64, 0, stream>>>((const u16*)d_in[0], flag);
  {
    CvtArgs ca;
    for (int i = 0; i < 23; ++i) {
      int ii = (i < n_in) ? i : (n_in - 1);
      ca.src[i] = d_in[ii];
      ca.aoff[i] = (int)aoffs[ii];
      ca.n[i] = in_sizes[ii];
    }
    ca.total = (int)total;
    convert_fused<<<(unsigned)((total / 4 + 255) / 256), 256, 0, stream>>>(ca, arena, flag);
  }

  // 1. transpose all weights to [N,K]
  transpose_kernel<<<dim3(16, 16), 256, 0, stream>>>(c_Wq, WqT, 512, 512);
  transpose_kernel<<<dim3(16, 16), 256, 0, stream>>>(c_Wk, WkT, 512, 512);
  transpose_kernel<<<dim3(16, 16), 256, 0, stream>>>(c_Wv, WvT, 512, 512);
  transpose_kernel<<<dim3(16, 16), 256, 0, stream>>>(c_Wm, WmT, 512, 512);
  transpose_kernel<<<dim3(16, 16), 256, 0, stream>>>(c_Wp, WpT, 512, 512);
  transpose_kernel<<<dim3(32, 16), 256, 0, stream>>>(c_Wig, WigT, 512, 1024);
  transpose_kernel<<<dim3(32, 16), 256, 0, stream>>>(c_Wmg, WmgT, 512, 1024);

  // 2. projections of ipts (loop-invariant)
  gemm_bt<0><<<dim3(32, 4), 256, 0, stream>>>(c_ipts, WpT, c_bp, inp, 4096, 512);
  gemm_bt<0><<<dim3(32, 4), 256, 0, stream>>>(inp, WkT, c_bk, kbase, 4096, 512);
  gemm_bt<0><<<dim3(32, 4), 256, 0, stream>>>(inp, WvT, c_bv, vbase, 4096, 512);
  gemm_bt<0><<<dim3(32, 4), 256, 0, stream>>>(inp, WqT, c_bq, q2, 4096, 512);

  // 3. input gate term gi
  redmean_kernel<<<dim3(32, 2), 256, 0, stream>>>(inp, c_repw, rmean);
  gemm_bt<0><<<dim3(1, 8), 256, 0, stream>>>(rmean, WigT, c_big, gi, 32, 1024);

  // 4. the 4 relational blocks
  const u16* memsrc = c_mem;
  for (int it = 0; it < 4; ++it) {
    gemm_bt<0><<<dim3(323, 4), 256, 0, stream>>>(memsrc, WqT, c_bq, qbuf, 41280, 512);
    attn1_kernel<<<dim3(6, 256), 256, 0, stream>>>(qbuf, kbase, vbase, obuf);
    ln_kernel<<<dim3(41280), 64, 0, stream>>>(memsrc, obuf, membf, c_g1, c_b1);
    gemm_bt<1><<<dim3(323, 4), 256, 0, stream>>>(membf, WmT, c_bm, qbuf, 41280, 512);
    gemm_bt<1><<<dim3(323, 4), 256, 0, stream>>>(qbuf, WmT, c_bm, obuf, 41280, 512);
    ln_kernel<<<dim3(41280), 64, 0, stream>>>(membf, obuf, membf, c_g2, c_b2);
    memsrc = membf;
  }

  // 5. gates in two passes (gm split by output-column half; qbuf free -> tanh(memory))
  tanhmem_kernel<<<dim3(2641920 / 256), 256, 0, stream>>>(c_mem, qbuf, 2641920);
  gemm_bt<0><<<dim3(323, 4), 256, 0, stream>>>(qbuf, WmgT, c_bmg, gmbuf, 41280, 512);
  gatesA_kernel<<<dim3(41280), 512, 0, stream>>>(gmbuf, gi, membf, c_ib, nmbf);
  gemm_bt<0><<<dim3(323, 4), 256, 0, stream>>>(qbuf, WmgT + (size_t)512 * 512, c_bmg + 512, gmbuf, 41280, 512);
  gatesB_kernel<<<dim3(41280), 512, 0, stream>>>(gmbuf, gi, nmbf, c_mem, c_fb, nmbf, d_out, flag);

  // 6. hx attention: q from inp, k/v from next_memory (output 1)
  gemm_bt<0><<<dim3(323, 4), 256, 0, stream>>>(nmbf, WkT, c_bk, qbuf, 41280, 512);
  gemm_bt<0><<<dim3(323, 4), 256, 0, stream>>>(nmbf, WvT, c_bv, obuf, 41280, 512);
  attn2_partial<<<dim3(256, 4), 128, 0, stream>>>(q2, qbuf, obuf, pacc, pml);
  attn2_merge<<<dim3(32768), 64, 0, stream>>>(pacc, pml, d_out, flag);
}

// Round 4
// 2169.796 us; speedup vs baseline: 2.0205x; 1.3489x over previous
//
#include <hip/hip_runtime.h>
#include <stdint.h>

typedef uint16_t u16;
typedef uint32_t u32;

#define DEVI __device__ __forceinline__

DEVI float b2f(u16 u) { return __uint_as_float(((u32)u) << 16); }
DEVI float blo(u32 u) { return __uint_as_float(u << 16); }
DEVI float bhi(u32 u) { return __uint_as_float(u & 0xffff0000u); }
DEVI u16 f2b(float f) {
  u32 x = __float_as_uint(f);
  return (u16)((x + 0x7fffu + ((x >> 16) & 1u)) >> 16);
}
DEVI u32 pack2(float a, float b) { return (u32)f2b(a) | ((u32)f2b(b) << 16); }
DEVI float sigm(float x) { return 1.f / (1.f + __expf(-x)); }

typedef __bf16 bf16x8 __attribute__((ext_vector_type(8)));
typedef float f32x4 __attribute__((ext_vector_type(4)));

#define MFMA16(a, b, c) __builtin_amdgcn_mfma_f32_16x16x32_bf16(a, b, c, 0, 0, 0)

DEVI void gll16(const void* g, void* l) {
  __builtin_amdgcn_global_load_lds((const __attribute__((address_space(1))) void*)g,
                                   (__attribute__((address_space(3))) void*)l, 16, 0, 0);
}

// ---------------- input dtype detect: 0 = bf16, 1 = fp32 ----------------
__global__ void detect_kernel(const u16* __restrict__ x, int* __restrict__ flag) {
  if (threadIdx.x == 0 && blockIdx.x == 0) {
    int f = 0;
    for (int i = 0; i < 64; ++i) {
      u16 u = x[2 * i];  // low half if fp32
      int e = (u >> 7) & 0xFF;
      if (e > 131) f = 1;  // |val| >= 32 impossible for randn bf16
    }
    *flag = f;
  }
}

// ---------------- fused convert: all inputs -> bf16 arena, one dispatch ----------------
struct CvtArgs {
  const void* src[23];
  int aoff[23];
  int n[23];
  int total;
};

__global__ __launch_bounds__(256) void convert_fused(CvtArgs a, u16* __restrict__ arena,
                                                     const int* __restrict__ flag) {
  int e4 = (blockIdx.x * 256 + threadIdx.x) * 4;
  if (e4 >= a.total) return;
  const char* sp = (const char*)a.src[0];
  int rel = e4, cnt = a.n[0];
#pragma unroll
  for (int j = 1; j < 23; ++j)
    if (e4 >= a.aoff[j]) { sp = (const char*)a.src[j]; rel = e4 - a.aoff[j]; cnt = a.n[j]; }
  const bool f32 = (*flag != 0);
  if (rel + 3 < cnt) {
    if (f32) {
      float4 v = *(const float4*)(sp + (size_t)rel * 4);
      uint2 o;
      o.x = pack2(v.x, v.y);
      o.y = pack2(v.z, v.w);
      *(uint2*)(arena + e4) = o;
    } else {
      *(uint2*)(arena + e4) = *(const uint2*)(sp + (size_t)rel * 2);
    }
  } else {
#pragma unroll
    for (int k = 0; k < 4; ++k) {
      u16 o = 0;
      if (rel + k < cnt)
        o = f32 ? f2b(((const float*)sp)[rel + k]) : ((const u16*)sp)[rel + k];
      arena[e4 + k] = o;
    }
  }
}

// ---------------- GEMM (m97 pattern, verified R3) ----------------
template <int ACT>
__global__ __launch_bounds__(256, 3) void gemm_bt(
    const u16* __restrict__ A, const u16* __restrict__ Bt,
    const u16* __restrict__ bias, u16* __restrict__ Co, int Mtot, int Ntot) {
  __shared__ __align__(16) u16 aT[128 * 64];
  __shared__ __align__(16) u16 bT[128 * 64];
  const int tid = threadIdx.x;
  const int lane = tid & 63;
  const int w = tid >> 6;
  const int m0 = blockIdx.x * 128;
  const int n0 = blockIdx.y * 128;
  const int wm = (w & 1) << 6;
  const int wn = (w >> 1) << 6;

  f32x4 acc[4][4] = {};

  const u16* ga[4];
  const u16* gb[4];
#pragma unroll
  for (int q = 0; q < 4; ++q) {
    int j = q * 256 + tid;
    int r = j >> 3, s = j & 7;
    int c = (s ^ (r & 7)) * 8;
    int ra = m0 + r;
    if (ra >= Mtot) ra = Mtot - 1;
    ga[q] = A + (size_t)ra * 512 + c;
    gb[q] = Bt + (size_t)(n0 + r) * 512 + c;
  }

  for (int ko = 0; ko < 8; ++ko) {
    const int k0 = ko * 64;
#pragma unroll
    for (int q = 0; q < 4; ++q) {
      int j = q * 256 + tid;
      gll16(ga[q] + k0, aT + j * 8);
      gll16(gb[q] + k0, bT + j * 8);
    }
    __syncthreads();
#pragma unroll
    for (int ks = 0; ks < 2; ++ks) {
      bf16x8 af[4], bfr[4];
#pragma unroll
      for (int i = 0; i < 4; ++i) {
        int cch = ks * 4 + (lane >> 4);
        int r = wm + i * 16 + (lane & 15);
        af[i] = *(const bf16x8*)(aT + (r * 8 + (cch ^ (r & 7))) * 8);
        int rn = wn + i * 16 + (lane & 15);
        bfr[i] = *(const bf16x8*)(bT + (rn * 8 + (cch ^ (rn & 7))) * 8);
      }
#pragma unroll
      for (int i = 0; i < 4; ++i)
#pragma unroll
        for (int jn = 0; jn < 4; ++jn)
          acc[i][jn] = MFMA16(af[i], bfr[jn], acc[i][jn]);
    }
    __syncthreads();
  }

  const int cl = lane & 15;
  const int rg = lane >> 4;
#pragma unroll
  for (int jn = 0; jn < 4; ++jn) {
    int col = n0 + wn + jn * 16 + cl;
    float bv = b2f(bias[col]);
#pragma unroll
    for (int i = 0; i < 4; ++i) {
      int rowb = m0 + wm + i * 16 + rg * 4;
#pragma unroll
      for (int rr = 0; rr < 4; ++rr) {
        int row = rowb + rr;
        if (row < Mtot) {
          float vv = acc[i][jn][rr] + bv;
          if (ACT) vv = fmaxf(vv, 0.f);
          Co[(size_t)row * Ntot + col] = f2b(vv);
        }
      }
    }
  }
}

// ---------------- weight transpose ----------------
__global__ __launch_bounds__(256) void transpose_kernel(const u16* __restrict__ in,
                                                        u16* __restrict__ outb, int K, int N) {
  __shared__ u16 tile[32][33];
  const int tx = threadIdx.x & 31, ty = threadIdx.x >> 5;
  const int bx = blockIdx.x * 32;
  const int by = blockIdx.y * 32;
#pragma unroll
  for (int i = 0; i < 32; i += 8) tile[ty + i][tx] = in[(size_t)(by + ty + i) * N + bx + tx];
  __syncthreads();
#pragma unroll
  for (int i = 0; i < 32; i += 8) outb[(size_t)(bx + ty + i) * K + by + tx] = tile[tx][ty + i];
}

// ---------------- tanh(memory) ----------------
__global__ void tanhmem_kernel(const u16* __restrict__ mi, u16* __restrict__ th, int n8) {
  int i = blockIdx.x * 256 + threadIdx.x;
  if (i >= n8) return;
  uint4 u = ((const uint4*)mi)[i];
  uint4 t;
  t.x = pack2(tanhf(blo(u.x)), tanhf(bhi(u.x)));
  t.y = pack2(tanhf(blo(u.y)), tanhf(bhi(u.y)));
  t.z = pack2(tanhf(blo(u.z)), tanhf(bhi(u.z)));
  t.w = pack2(tanhf(blo(u.w)), tanhf(bhi(u.w)));
  ((uint4*)th)[i] = t;
}

// ---------------- rmean ----------------
__global__ void redmean_kernel(const u16* __restrict__ inp, const u16* __restrict__ repw,
                               u16* __restrict__ outb) {
  const int b = blockIdx.x;
  const int c = blockIdx.y * 256 + threadIdx.x;
  const float rw = b2f(repw[c]);
  float s = 0.f;
  for (int t = 0; t < 128; ++t)
    s += fmaxf(rw * b2f(inp[(size_t)(b * 128 + t) * 512 + c]), 0.f);
  outb[b * 512 + c] = f2b(s * (1.f / 128.f));
}

// ---------------- LayerNorm ----------------
__global__ __launch_bounds__(64) void ln_kernel(const u16* __restrict__ src,
                                                const u16* __restrict__ addb,
                                                u16* __restrict__ dst,
                                                const u16* __restrict__ g,
                                                const u16* __restrict__ bb) {
  const int row = blockIdx.x;
  const int lane = threadIdx.x;
  const u16* srow = src + (size_t)row * 512;
  const u16* arow = addb + (size_t)row * 512;
  float x[8];
  float s = 0.f;
#pragma unroll
  for (int i = 0; i < 8; ++i) {
    int c = lane + i * 64;
    x[i] = b2f(srow[c]) + b2f(arow[c]);
    s += x[i];
  }
#pragma unroll
  for (int off = 32; off > 0; off >>= 1) s += __shfl_xor(s, off, 64);
  const float mu = s * (1.f / 512.f);
  float v = 0.f;
#pragma unroll
  for (int i = 0; i < 8; ++i) {
    float d = x[i] - mu;
    v = fmaf(d, d, v);
  }
#pragma unroll
  for (int off = 32; off > 0; off >>= 1) v += __shfl_xor(v, off, 64);
  const float rstd = rsqrtf(v * (1.f / 512.f) + 1e-5f);
  u16* orow = dst + (size_t)row * 512;
#pragma unroll
  for (int i = 0; i < 8; ++i) {
    int c = lane + i * 64;
    orow[c] = f2b(fmaf((x[i] - mu) * rstd, b2f(g[c]), b2f(bb[c])));
  }
}

// ---------------- attention 1 (MFMA): 1290 q (mem), 128 k (inp), top-8 mask ----------------
// Phase 1: S = Q.K^T via MFMA into LDS (bf16, scaled). Phase 2: thread=query scans its
// contiguous score row for top-8 + softmax denom; gathers 8 V rows from LDS.
__global__ __launch_bounds__(256, 2) void attn1_mfma(const u16* __restrict__ q,
                                                     const u16* __restrict__ kb,
                                                     const u16* __restrict__ vb,
                                                     u16* __restrict__ o) {
  __shared__ __align__(16) u16 Kl[128 * 64];   // swizzled [key][dim]
  __shared__ __align__(16) u16 Vl[128 * 72];   // [key][dim], pad 72
  __shared__ __align__(16) u16 Sl[128 * 132];  // [qlocal][key], stride 132 (b64-aligned, 2-way banks)
  const int tid = threadIdx.x;
  const int lane = tid & 63;
  const int w = tid >> 6;
  const int quad = lane >> 4;
  const int l15 = lane & 15;
  const int qb = blockIdx.x;
  const int bh = blockIdx.y;
  const int b = bh >> 3, h = bh & 7;

#pragma unroll
  for (int qq = 0; qq < 4; ++qq) {
    int j = qq * 256 + tid;
    int r = j >> 3, s = j & 7;
    gll16(kb + (size_t)(b * 128 + r) * 512 + h * 64 + (s ^ (r & 7)) * 8, Kl + j * 8);
  }
#pragma unroll
  for (int qq = 0; qq < 4; ++qq) {
    int j = qq * 256 + tid;
    int t = j >> 3, d8 = j & 7;
    uint4 u = *(const uint4*)(vb + (size_t)(b * 128 + t) * 512 + h * 64 + d8 * 8);
    *(uint4*)(Vl + t * 72 + d8 * 8) = u;
  }

  bf16x8 aq[2][2];
  {
    int r0 = qb * 128 + w * 32 + l15;
    int ra = min(r0, 1289), rb_ = min(r0 + 16, 1289);
    const u16* qa = q + (size_t)(b * 1290 + ra) * 512 + h * 64 + quad * 8;
    const u16* qc = q + (size_t)(b * 1290 + rb_) * 512 + h * 64 + quad * 8;
    aq[0][0] = *(const bf16x8*)(qa);
    aq[0][1] = *(const bf16x8*)(qa + 32);
    aq[1][0] = *(const bf16x8*)(qc);
    aq[1][1] = *(const bf16x8*)(qc + 32);
  }
  __syncthreads();

  f32x4 sa[2][8] = {};
#pragma unroll
  for (int ks = 0; ks < 2; ++ks) {
#pragma unroll
    for (int jn = 0; jn < 8; ++jn) {
      int n = jn * 16 + l15;
      int cch = ks * 4 + quad;
      bf16x8 bk = *(const bf16x8*)(Kl + (n * 8 + (cch ^ (n & 7))) * 8);
      sa[0][jn] = MFMA16(aq[0][ks], bk, sa[0][jn]);
      sa[1][jn] = MFMA16(aq[1][ks], bk, sa[1][jn]);
    }
  }
#pragma unroll
  for (int i = 0; i < 2; ++i)
#pragma unroll
    for (int jn = 0; jn < 8; ++jn)
#pragma unroll
      for (int r = 0; r < 4; ++r)
        Sl[(w * 32 + i * 16 + quad * 4 + r) * 132 + jn * 16 + l15] = f2b(sa[i][jn][r] * 0.125f);
  __syncthreads();

  if (tid < 128) {
    int qglob = qb * 128 + tid;
    if (qglob < 1290) {
      const u16* srow = Sl + tid * 132;
      float mx = -1e30f;
      float tv[8];
      int ti[8];
#pragma unroll
      for (int j = 0; j < 8; ++j) { tv[j] = -1e30f; ti[j] = 0; }
      // pass 1: max + top-8 (strict > keeps lower index on ties — jax top_k)
      for (int c = 0; c < 32; ++c) {
        uint2 u = *(const uint2*)(srow + c * 4);
        float v_[4] = {blo(u.x), bhi(u.x), blo(u.y), bhi(u.y)};
#pragma unroll
        for (int k4 = 0; k4 < 4; ++k4) {
          float s = v_[k4];
          mx = fmaxf(mx, s);
          if (s > tv[7]) {
            float cv = s;
            int ci = c * 4 + k4;
#pragma unroll
            for (int j = 0; j < 8; ++j) {
              bool gt = cv > tv[j];
              float ov = tv[j]; int oi = ti[j];
              tv[j] = gt ? cv : ov; ti[j] = gt ? ci : oi;
              cv = gt ? ov : cv;  ci = gt ? oi : ci;
            }
          }
        }
      }
      // pass 2: denominator over ALL keys (mask applied post-softmax in reference)
      float l = 0.f;
      for (int c = 0; c < 32; ++c) {
        uint2 u = *(const uint2*)(srow + c * 4);
        l += __expf(blo(u.x) - mx) + __expf(bhi(u.x) - mx) +
             __expf(blo(u.y) - mx) + __expf(bhi(u.y) - mx);
      }
      float oacc[64];
#pragma unroll
      for (int d = 0; d < 64; ++d) oacc[d] = 0.f;
      const float invl = 1.f / l;
#pragma unroll
      for (int j = 0; j < 8; ++j) {
        float p = __expf(tv[j] - mx) * invl;
        const u16* vrow = Vl + ti[j] * 72;
#pragma unroll
        for (int d8 = 0; d8 < 8; ++d8) {
          uint4 u = *(const uint4*)(vrow + d8 * 8);
          oacc[d8 * 8 + 0] = fmaf(p, blo(u.x), oacc[d8 * 8 + 0]);
          oacc[d8 * 8 + 1] = fmaf(p, bhi(u.x), oacc[d8 * 8 + 1]);
          oacc[d8 * 8 + 2] = fmaf(p, blo(u.y), oacc[d8 * 8 + 2]);
          oacc[d8 * 8 + 3] = fmaf(p, bhi(u.y), oacc[d8 * 8 + 3]);
          oacc[d8 * 8 + 4] = fmaf(p, blo(u.z), oacc[d8 * 8 + 4]);
          oacc[d8 * 8 + 5] = fmaf(p, bhi(u.z), oacc[d8 * 8 + 5]);
          oacc[d8 * 8 + 6] = fmaf(p, blo(u.w), oacc[d8 * 8 + 6]);
          oacc[d8 * 8 + 7] = fmaf(p, bhi(u.w), oacc[d8 * 8 + 7]);
        }
      }
      u32* orow = (u32*)(o + (size_t)(b * 1290 + qglob) * 512 + h * 64);
#pragma unroll
      for (int d2 = 0; d2 < 32; ++d2) orow[d2] = pack2(oacc[2 * d2], oacc[2 * d2 + 1]);
    }
  }
}

// ---------------- attention 2 (MFMA flash): 128 q (inp), 1290 k (next_memory) ----------------
__global__ __launch_bounds__(256, 2) void attn2_mfma(const u16* __restrict__ q2,
                                                     const u16* __restrict__ k2,
                                                     const u16* __restrict__ v2,
                                                     float* __restrict__ pacc,
                                                     float* __restrict__ pml) {
  __shared__ __align__(16) u16 Kl[64 * 64];      // swizzled [key][dim]
  __shared__ __align__(16) u16 VT[64 * 72];      // [dim][key], stride 72
  __shared__ __align__(16) u16 Pl[4 * 32 * 72];  // per-wave P [32q][64k]
  const int tid = threadIdx.x;
  const int lane = tid & 63;
  const int w = tid >> 6;
  const int quad = lane >> 4;
  const int l15 = lane & 15;
  const int bh = blockIdx.x;
  const int b = bh >> 3, h = bh & 7;
  const int part = blockIdx.y;
  const int kstart = (part * 1290) >> 2;
  const int kend = ((part + 1) * 1290) >> 2;

  bf16x8 aq[2][2];
  {
    int r0 = b * 128 + w * 32 + l15;
    const u16* qa = q2 + (size_t)r0 * 512 + h * 64 + quad * 8;
    aq[0][0] = *(const bf16x8*)(qa);
    aq[0][1] = *(const bf16x8*)(qa + 32);
    aq[1][0] = *(const bf16x8*)(qa + 16 * 512);
    aq[1][1] = *(const bf16x8*)(qa + 16 * 512 + 32);
  }

  f32x4 oa[2][4] = {};
  float m_[2][4], l_[2][4];
#pragma unroll
  for (int i = 0; i < 2; ++i)
#pragma unroll
    for (int r = 0; r < 4; ++r) { m_[i][r] = -1e30f; l_[i][r] = 0.f; }

  const int nk = kend - kstart;
  for (int kt = 0; kt < nk; kt += 64) {
    __syncthreads();
    // stage K swizzled (gll16)
#pragma unroll
    for (int qq = 0; qq < 2; ++qq) {
      int j = qq * 256 + tid;
      int r = j >> 3, s = j & 7;
      int kg = kstart + kt + r;
      if (kg >= kend) kg = kend - 1;
      gll16(k2 + (size_t)(b * 1290 + kg) * 512 + h * 64 + (s ^ (r & 7)) * 8, Kl + j * 8);
    }
    // stage V transposed: lane r = key, dc = dim chunk (write banks: const + r/2 -> 2-way free)
    {
      int r = tid & 63;
      int kg = kstart + kt + r;
      if (kg >= kend) kg = kend - 1;
      const u16* vrow = v2 + (size_t)(b * 1290 + kg) * 512 + h * 64;
#pragma unroll
      for (int p = 0; p < 2; ++p) {
        int dc = (tid >> 6) + p * 4;
        uint4 u = *(const uint4*)(vrow + dc * 8);
        u16 tmp[8];
        *(uint4*)tmp = u;
#pragma unroll
        for (int jj = 0; jj < 8; ++jj) VT[(dc * 8 + jj) * 72 + r] = tmp[jj];
      }
    }
    __syncthreads();

    // S = Q.K^T
    f32x4 sa[2][4] = {};
#pragma unroll
    for (int ks = 0; ks < 2; ++ks) {
#pragma unroll
      for (int jn = 0; jn < 4; ++jn) {
        int n = jn * 16 + l15;
        int cch = ks * 4 + quad;
        bf16x8 bk = *(const bf16x8*)(Kl + (n * 8 + (cch ^ (n & 7))) * 8);
        sa[0][jn] = MFMA16(aq[0][ks], bk, sa[0][jn]);
        sa[1][jn] = MFMA16(aq[1][ks], bk, sa[1][jn]);
      }
    }

    // online softmax (C-layout: col=l15 is key, row=quad*4+r is query) + P to LDS
    u16* pw = Pl + w * (32 * 72);
#pragma unroll
    for (int i = 0; i < 2; ++i) {
      float rmax[4] = {-1e30f, -1e30f, -1e30f, -1e30f};
#pragma unroll
      for (int jn = 0; jn < 4; ++jn) {
        int kg = kstart + kt + jn * 16 + l15;
        bool val = kg < kend;
#pragma unroll
        for (int r = 0; r < 4; ++r) {
          float s = sa[i][jn][r] * 0.125f;
          s = val ? s : -1e30f;
          sa[i][jn][r] = s;
          rmax[r] = fmaxf(rmax[r], s);
        }
      }
#pragma unroll
      for (int off = 1; off < 16; off <<= 1)
#pragma unroll
        for (int r = 0; r < 4; ++r) rmax[r] = fmaxf(rmax[r], __shfl_xor(rmax[r], off, 64));
      float alpha[4];
#pragma unroll
      for (int r = 0; r < 4; ++r) {
        float mn = fmaxf(m_[i][r], rmax[r]);
        alpha[r] = __expf(m_[i][r] - mn);
        m_[i][r] = mn;
      }
      float lsum[4] = {0.f, 0.f, 0.f, 0.f};
#pragma unroll
      for (int jn = 0; jn < 4; ++jn)
#pragma unroll
        for (int r = 0; r < 4; ++r) {
          float p = __expf(sa[i][jn][r] - m_[i][r]);
          sa[i][jn][r] = p;
          lsum[r] += p;
        }
#pragma unroll
      for (int off = 1; off < 16; off <<= 1)
#pragma unroll
        for (int r = 0; r < 4; ++r) lsum[r] += __shfl_xor(lsum[r], off, 64);
#pragma unroll
      for (int r = 0; r < 4; ++r) l_[i][r] = l_[i][r] * alpha[r] + lsum[r];
#pragma unroll
      for (int jd = 0; jd < 4; ++jd)
#pragma unroll
        for (int r = 0; r < 4; ++r) oa[i][jd][r] *= alpha[r];
#pragma unroll
      for (int jn = 0; jn < 4; ++jn) {
        int col = jn * 16 + l15;
#pragma unroll
        for (int r = 0; r < 4; ++r)
          pw[(i * 16 + quad * 4 + r) * 72 + col] = f2b(sa[i][jn][r]);
      }
    }

    // O += P.V   (A = P from per-wave LDS, B = VT)
#pragma unroll
    for (int ks = 0; ks < 2; ++ks) {
      bf16x8 ap[2];
#pragma unroll
      for (int i = 0; i < 2; ++i)
        ap[i] = *(const bf16x8*)(pw + (i * 16 + l15) * 72 + ks * 32 + quad * 8);
#pragma unroll
      for (int jd = 0; jd < 4; ++jd) {
        bf16x8 bv_ = *(const bf16x8*)(VT + (jd * 16 + l15) * 72 + ks * 32 + quad * 8);
        oa[0][jd] = MFMA16(ap[0], bv_, oa[0][jd]);
        oa[1][jd] = MFMA16(ap[1], bv_, oa[1][jd]);
      }
    }
  }

  // store partials (C-layout scatter)
  float* pa = pacc + (size_t)(part * 256 + bh) * 128 * 64;
#pragma unroll
  for (int i = 0; i < 2; ++i) {
    int row = w * 32 + i * 16 + quad * 4;
#pragma unroll
    for (int r = 0; r < 4; ++r)
#pragma unroll
      for (int jd = 0; jd < 4; ++jd)
        pa[(size_t)(row + r) * 64 + jd * 16 + l15] = oa[i][jd][r];
    if (l15 == 0) {
#pragma unroll
      for (int r = 0; r < 4; ++r) {
        size_t pi = (size_t)(part * 256 + bh) * 128 + row + r;
        pml[pi * 2 + 0] = m_[i][r];
        pml[pi * 2 + 1] = l_[i][r];
      }
    }
  }
}

__global__ __launch_bounds__(64) void attn2_merge(const float* __restrict__ pacc,
                                                  const float* __restrict__ pml,
                                                  void* __restrict__ outp,
                                                  const int* __restrict__ flag) {
  const int qi = blockIdx.x;  // bh*128 + t
  const int bh = qi >> 7, t = qi & 127;
  const int b = bh >> 3, h = bh & 7;
  const int lane = threadIdx.x;
  float mv[4], lv[4];
  float m0 = -1e30f;
#pragma unroll
  for (int i = 0; i < 4; ++i) {
    size_t pi = (size_t)(i * 256 + bh) * 128 + t;
    mv[i] = pml[pi * 2];
    lv[i] = pml[pi * 2 + 1];
    m0 = fmaxf(m0, mv[i]);
  }
  float L = 0.f, accd = 0.f;
#pragma unroll
  for (int i = 0; i < 4; ++i) {
    size_t pi = (size_t)(i * 256 + bh) * 128 + t;
    float e = __expf(mv[i] - m0);
    L += lv[i] * e;
    accd += pacc[pi * 64 + lane] * e;
  }
  float v = accd / L;
  size_t off = (size_t)41280 * 512 + ((size_t)(b * 128 + t) * 512 + h * 64 + lane);
  if (*flag) ((float*)outp)[off] = v; else ((u16*)outp)[off] = f2b(v);
}

// ---------------- gates ----------------
__global__ __launch_bounds__(512) void gatesA_kernel(const u16* __restrict__ gmb,
                                                     const u16* __restrict__ gi,
                                                     const u16* __restrict__ memfin,
                                                     const u16* __restrict__ ibp,
                                                     u16* __restrict__ pnm) {
  const int r = blockIdx.x;
  const int b = r / 1290;
  const int c = threadIdx.x;
  const float ibias = b2f(ibp[0]);
  size_t idx = (size_t)r * 512 + c;
  float ig = sigm(b2f(gmb[idx]) + b2f(gi[b * 1024 + c]) + ibias);
  pnm[idx] = f2b(ig * tanhf(b2f(memfin[idx])));
}

__global__ __launch_bounds__(512) void gatesB_kernel(const u16* __restrict__ gmb,
                                                     const u16* __restrict__ gi,
                                                     const u16* __restrict__ pnm,
                                                     const u16* __restrict__ mem_in,
                                                     const u16* __restrict__ fbp,
                                                     u16* __restrict__ nmbf,
                                                     void* __restrict__ outp,
                                                     const int* __restrict__ flag) {
  const int r = blockIdx.x;
  const int b = r / 1290;
  const int c = threadIdx.x;
  const float fbias = b2f(fbp[0]);
  size_t idx = (size_t)r * 512 + c;
  float fg = sigm(b2f(gmb[idx]) + b2f(gi[b * 1024 + 512 + c]) + fbias);
  float v = b2f(pnm[idx]) + fg * b2f(mem_in[idx]);
  nmbf[idx] = f2b(v);
  if (*flag) ((float*)outp)[idx] = v; else ((u16*)outp)[idx] = f2b(v);
}

extern "C" void kernel_launch(void* const* d_in, const int* in_sizes, int n_in,
                              void* d_out, int out_size, void* d_ws, size_t ws_size,
                              hipStream_t stream) {
  (void)out_size; (void)ws_size;
  char* ws = (char*)d_ws;
  size_t off = 0;
  auto alloc = [&](size_t bytes) {
    char* p = ws + off;
    off += (bytes + 255) & ~(size_t)255;
    return (void*)p;
  };

  int* flag = (int*)alloc(256);

  size_t aoffs[32];
  size_t total = 0;
  for (int i = 0; i < n_in; ++i) {
    aoffs[i] = total;
    total += ((size_t)in_sizes[i] + 127) & ~(size_t)127;
  }
  u16* arena = (u16*)alloc(total * 2);

  const u16* c_ipts = arena + aoffs[0];
  const u16* c_mem  = arena + aoffs[1];
  const u16* c_Wq = arena + aoffs[2];  const u16* c_bq = arena + aoffs[3];
  const u16* c_Wk = arena + aoffs[4];  const u16* c_bk = arena + aoffs[5];
  const u16* c_Wv = arena + aoffs[6];  const u16* c_bv = arena + aoffs[7];
  const u16* c_Wm = arena + aoffs[8];  const u16* c_bm = arena + aoffs[9];
  const u16* c_g1 = arena + aoffs[10]; const u16* c_b1 = arena + aoffs[11];
  const u16* c_g2 = arena + aoffs[12]; const u16* c_b2 = arena + aoffs[13];
  const u16* c_Wp = arena + aoffs[14]; const u16* c_bp = arena + aoffs[15];
  const u16* c_repw = arena + aoffs[16];
  const u16* c_Wig = arena + aoffs[17]; const u16* c_big = arena + aoffs[18];
  const u16* c_Wmg = arena + aoffs[19]; const u16* c_bmg = arena + aoffs[20];
  const u16* c_fb = arena + aoffs[21];
  const u16* c_ib = arena + aoffs[22];

  u16* WqT = (u16*)alloc(512 * 512 * 2);
  u16* WkT = (u16*)alloc(512 * 512 * 2);
  u16* WvT = (u16*)alloc(512 * 512 * 2);
  u16* WmT = (u16*)alloc(512 * 512 * 2);
  u16* WpT = (u16*)alloc(512 * 512 * 2);
  u16* WigT = (u16*)alloc(512 * 1024 * 2);
  u16* WmgT = (u16*)alloc(512 * 1024 * 2);
  u16* inp = (u16*)alloc((size_t)4096 * 512 * 2);
  u16* kbase = (u16*)alloc((size_t)4096 * 512 * 2);
  u16* vbase = (u16*)alloc((size_t)4096 * 512 * 2);
  u16* q2 = (u16*)alloc((size_t)4096 * 512 * 2);
  u16* rmean = (u16*)alloc(32 * 512 * 2);
  u16* gi = (u16*)alloc(32 * 1024 * 2);
  u16* membf = (u16*)alloc((size_t)41280 * 512 * 2);
  u16* qbuf = (u16*)alloc((size_t)41280 * 512 * 2);
  u16* obuf = (u16*)alloc((size_t)41280 * 512 * 2);
  u16* gmbuf = (u16*)alloc((size_t)41280 * 512 * 2);
  u16* nmbf = (u16*)alloc((size_t)41280 * 512 * 2);
  float* pacc = (float*)(void*)gmbuf;  // 33.5MB, gmbuf dead after gatesB
  float* pml = (float*)((char*)(void*)gmbuf + (size_t)4 * 32768 * 64 * 4);

  detect_kernel<<<1, 64, 0, stream>>>((const u16*)d_in[0], flag);
  {
    CvtArgs ca;
    for (int i = 0; i < 23; ++i) {
      int ii = (i < n_in) ? i : (n_in - 1);
      ca.src[i] = d_in[ii];
      ca.aoff[i] = (int)aoffs[ii];
      ca.n[i] = in_sizes[ii];
    }
    ca.total = (int)total;
    convert_fused<<<(unsigned)((total / 4 + 255) / 256), 256, 0, stream>>>(ca, arena, flag);
  }

  transpose_kernel<<<dim3(16, 16), 256, 0, stream>>>(c_Wq, WqT, 512, 512);
  transpose_kernel<<<dim3(16, 16), 256, 0, stream>>>(c_Wk, WkT, 512, 512);
  transpose_kernel<<<dim3(16, 16), 256, 0, stream>>>(c_Wv, WvT, 512, 512);
  transpose_kernel<<<dim3(16, 16), 256, 0, stream>>>(c_Wm, WmT, 512, 512);
  transpose_kernel<<<dim3(16, 16), 256, 0, stream>>>(c_Wp, WpT, 512, 512);
  transpose_kernel<<<dim3(32, 16), 256, 0, stream>>>(c_Wig, WigT, 512, 1024);
  transpose_kernel<<<dim3(32, 16), 256, 0, stream>>>(c_Wmg, WmgT, 512, 1024);

  gemm_bt<0><<<dim3(32, 4), 256, 0, stream>>>(c_ipts, WpT, c_bp, inp, 4096, 512);
  gemm_bt<0><<<dim3(32, 4), 256, 0, stream>>>(inp, WkT, c_bk, kbase, 4096, 512);
  gemm_bt<0><<<dim3(32, 4), 256, 0, stream>>>(inp, WvT, c_bv, vbase, 4096, 512);
  gemm_bt<0><<<dim3(32, 4), 256, 0, stream>>>(inp, WqT, c_bq, q2, 4096, 512);

  redmean_kernel<<<dim3(32, 2), 256, 0, stream>>>(inp, c_repw, rmean);
  gemm_bt<0><<<dim3(1, 8), 256, 0, stream>>>(rmean, WigT, c_big, gi, 32, 1024);

  const u16* memsrc = c_mem;
  for (int it = 0; it < 4; ++it) {
    gemm_bt<0><<<dim3(323, 4), 256, 0, stream>>>(memsrc, WqT, c_bq, qbuf, 41280, 512);
    attn1_mfma<<<dim3(11, 256), 256, 0, stream>>>(qbuf, kbase, vbase, obuf);
    ln_kernel<<<dim3(41280), 64, 0, stream>>>(memsrc, obuf, membf, c_g1, c_b1);
    gemm_bt<1><<<dim3(323, 4), 256, 0, stream>>>(membf, WmT, c_bm, qbuf, 41280, 512);
    gemm_bt<1><<<dim3(323, 4), 256, 0, stream>>>(qbuf, WmT, c_bm, obuf, 41280, 512);
    ln_kernel<<<dim3(41280), 64, 0, stream>>>(membf, obuf, membf, c_g2, c_b2);
    memsrc = membf;
  }

  tanhmem_kernel<<<dim3(2641920 / 256), 256, 0, stream>>>(c_mem, qbuf, 2641920);
  gemm_bt<0><<<dim3(323, 4), 256, 0, stream>>>(qbuf, WmgT, c_bmg, gmbuf, 41280, 512);
  gatesA_kernel<<<dim3(41280), 512, 0, stream>>>(gmbuf, gi, membf, c_ib, nmbf);
  gemm_bt<0><<<dim3(323, 4), 256, 0, stream>>>(qbuf, WmgT + (size_t)512 * 512, c_bmg + 512, gmbuf, 41280, 512);
  gatesB_kernel<<<dim3(41280), 512, 0, stream>>>(gmbuf, gi, nmbf, c_mem, c_fb, nmbf, d_out, flag);

  gemm_bt<0><<<dim3(323, 4), 256, 0, stream>>>(nmbf, WkT, c_bk, qbuf, 41280, 512);
  gemm_bt<0><<<dim3(323, 4), 256, 0, stream>>>(nmbf, WvT, c_bv, obuf, 41280, 512);
  attn2_mfma<<<dim3(256, 4), 256, 0, stream>>>(q2, qbuf, obuf, pacc, pml);
  attn2_merge<<<dim3(32768), 64, 0, stream>>>(pacc, pml, d_out, flag);
}